// Round 4
// baseline (375.465 us; speedup 1.0000x reference)
//
#include <hip/hip_runtime.h>

// RF grid-sample DAS beamforming.
// Shapes: d_tx[4,512,256] d_rx[128,512,256] apod[128,512,256] rf[4,128,3072] t0[4]
// out[4,512,256] fp32.
//
// R4: stall-bound fix. History: R0=93us (2 blocks/CU cap, scalar stream loads,
// 64 live regs at 64 VGPR). R1=120us (angle split: occupancy up but amortization
// halved). R3=121us (fp16-dup LDS halved conflicts -- confirmed, kept -- but T14
// register prefetch pushed ~94 live floats into a 64-VGPR allocation -> spills,
// visible as FETCH +46MB / WRITE +22MB).
// Changes vs R0:
//  - PXT 8->4 with CONTIGUOUS pixels per thread: drx/apod/d_tx are one float4
//    per iteration (1KB/wave coalesced) instead of 8 scalar loads; acc+dta live
//    state halves to 32 floats.
//  - TILES 32->64 => grid 1024 blocks => 3 blocks/CU (LDS-limited), 75% occ cap.
//    __launch_bounds__(512,6) pins VGPR<=84 so regalloc matches 3-block residency.
//  - All R0 amortization invariants preserved: total staging / d_tx / drx/apod /
//    atomic traffic identical (grid x TILE and grid x EPB unchanged).
//  - rf staged in LDS as DUPLICATED fp16 pairs lds[s]={rf[s],rf[s+1]} (4B):
//    one ds_read_b32 per interp; conflicts halve (R3-measured 1.04e7->5.2e6).
//    RNE converts (not cvt_pkrtz RTZ) for absmax margin.
//  - No register prefetch of rf (spill cause); rf is L2-resident (6MB), and
//    drx/ap float4 loads are issued before the barrier to hide under staging.
// Partial sums across 16 e-chunks via fp32 atomicAdd (out zeroed by memset;
// graph-capture safe).
// Data range: delay in [0,3070] => i1 <= 3071 = S-1: clamp is no-op safety;
// the duplicated pair at s=3071 (garbage second half) is never read.

#define A_N 4
#define E_N 128
#define S_N 3072
#define NPIX_N (512 * 256)
#define TPB 512                    // threads per block (8 waves)
#define PXT 4                      // contiguous pixels per thread
#define TILE (TPB * PXT)           // 2048 pixels per block
#define TILES (NPIX_N / TILE)      // 64
#define ESPLIT 16                  // e-chunks
#define EPB (E_N / ESPLIT)         // 8 elements per block
#define SIT ((A_N * (S_N / 4)) / TPB)  // 3072 float4-slots / 512 thr = 6

typedef __fp16 half2_t __attribute__((ext_vector_type(2)));

__global__ __launch_bounds__(TPB, 6) void das_kernel(
    const float* __restrict__ d_tx, const float* __restrict__ d_rx,
    const float* __restrict__ apod, const float* __restrict__ rf,
    const float* __restrict__ t0,  float* __restrict__ out)
{
    __shared__ __align__(16) half2_t lds_rf[A_N * S_N];   // 48 KB
    const int tid = threadIdx.x;
    const int px0 = blockIdx.x * TILE + tid * PXT;   // 4 contiguous pixels
    const int e0  = blockIdx.y * EPB;

    float4 acc[A_N];
    float4 dta[A_N];
#pragma unroll
    for (int a = 0; a < A_N; ++a) {
        const float t0a = t0[a];
        float4 v = *(const float4*)(d_tx + a * NPIX_N + px0);
        dta[a] = make_float4(v.x - t0a, v.y - t0a, v.z - t0a, v.w - t0a);
        acc[a] = make_float4(0.f, 0.f, 0.f, 0.f);
    }

    for (int ei = 0; ei < EPB; ++ei) {
        const int e = e0 + ei;
        // Stream loads issued before the barrier (no LDS dependency):
        // latency hides under staging + barrier.
        const float4 drx4 = *(const float4*)(d_rx + (size_t)e * NPIX_N + px0);
        const float4 ap4  = *(const float4*)(apod + (size_t)e * NPIX_N + px0);

        __syncthreads();   // previous iteration's gathers done before overwrite
#pragma unroll
        for (int j = 0; j < SIT; ++j) {
            int idx = tid + j * TPB;          // float4 slot 0..3071
            int a   = idx / (S_N / 4);        // 0..3
            int s4  = idx - a * (S_N / 4);    // 0..767
            const float* r = rf + a * (E_N * S_N) + e * S_N + s4 * 4;
            float4 v = *(const float4*)r;
            float  x = r[(s4 == (S_N / 4 - 1)) ? 3 : 4];  // clamped; pair at 3071 never read
            union { half2_t h[4]; float4 f; } u;
            u.h[0] = half2_t{(__fp16)v.x, (__fp16)v.y};   // RNE converts
            u.h[1] = half2_t{(__fp16)v.y, (__fp16)v.z};
            u.h[2] = half2_t{(__fp16)v.z, (__fp16)v.w};
            u.h[3] = half2_t{(__fp16)v.w, (__fp16)x};
            *(float4*)&lds_rf[a * S_N + s4 * 4] = u.f;
        }
        __syncthreads();

        const float* drxp = (const float*)&drx4;
        const float* app  = (const float*)&ap4;
#pragma unroll
        for (int k = 0; k < PXT; ++k) {
            const float drx = drxp[k];
            const float ap  = app[k];
#pragma unroll
            for (int a = 0; a < A_N; ++a) {
                float delay = ((const float*)&dta[a])[k] + drx;
                float x0 = floorf(delay);
                float w  = delay - x0;
                int i0 = (int)x0;
                i0 = min(max(i0, 0), S_N - 2);   // no-op for this data; safety
                half2_t hv = lds_rf[a * S_N + i0];   // one ds_read_b32: {v0,v1}
                float v0 = (float)hv[0];
                float v1 = (float)hv[1];
                ((float*)&acc[a])[k] += (v0 + w * (v1 - v0)) * ap;
            }
        }
    }

#pragma unroll
    for (int a = 0; a < A_N; ++a)
#pragma unroll
        for (int k = 0; k < PXT; ++k)
            atomicAdd(&out[a * NPIX_N + px0 + k], ((const float*)&acc[a])[k]);
}

extern "C" void kernel_launch(void* const* d_in, const int* in_sizes, int n_in,
                              void* d_out, int out_size, void* d_ws, size_t ws_size,
                              hipStream_t stream) {
    const float* d_tx = (const float*)d_in[0];
    const float* d_rx = (const float*)d_in[1];
    const float* apod = (const float*)d_in[2];
    const float* rf   = (const float*)d_in[3];
    const float* t0   = (const float*)d_in[4];
    float* out = (float*)d_out;

    hipMemsetAsync(out, 0, (size_t)out_size * sizeof(float), stream);
    dim3 grid(TILES, ESPLIT);
    das_kernel<<<grid, TPB, 0, stream>>>(d_tx, d_rx, apod, rf, t0, out);
}